// Round 10
// baseline (393.835 us; speedup 1.0000x reference)
//
#include <hip/hip_runtime.h>

typedef unsigned short u16;
typedef unsigned int   u32;
typedef unsigned long long u64;
typedef __attribute__((ext_vector_type(8))) short bf16x8;
typedef __attribute__((ext_vector_type(4))) float f32x4;

#define S_  2048
#define DH  64
#define DM  1024
#define BS  8192
#define CS  0.18033688011112042f   // 0.125 * log2(e)

static __device__ __forceinline__ float bf2f(u16 v){ return __uint_as_float(((u32)v)<<16); }
static __device__ __forceinline__ u16 f2bf(float f){
  u32 x = __float_as_uint(f);
  return (u16)((x + 0x7fffu + ((x>>16)&1u)) >> 16);   // RNE
}
#if __has_builtin(__builtin_amdgcn_cvt_pk_bf16_f32)
static __device__ __forceinline__ u32 pk2(float x, float y){
  typedef __attribute__((ext_vector_type(2))) __bf16 bf2v;
  union { bf2v v; u32 u; } c; c.v = __builtin_amdgcn_cvt_pk_bf16_f32(x, y); return c.u;
}
#else
static __device__ __forceinline__ u32 pk2(float x, float y){
  return (u32)f2bf(x) | ((u32)f2bf(y) << 16);
}
#endif
#if __has_builtin(__builtin_amdgcn_exp2f)
#define EXP2F(x) __builtin_amdgcn_exp2f(x)
#else
#define EXP2F(x) exp2f(x)
#endif

// async global->LDS, 16B/lane; LDS dest = wave-uniform base + lane*16
static __device__ __forceinline__ void dma16(const u16* g, const u16* l){
  __builtin_amdgcn_global_load_lds(
      (const __attribute__((address_space(1))) u32*)(u64)(uintptr_t)g,
      (__attribute__((address_space(3))) u32*)(u32)(u64)(uintptr_t)l, 16, 0, 0);
}

// 16B-aligned fragment load (single ds_read_b128)
static __device__ __forceinline__ bf16x8 frag16v(const u16* p){
  union { bf16x8 f; uint4 u; } w;
  w.u = *(const uint4*)p;
  return w.f;
}

// prep: four 1024x1024 weight transposes (f32/bf16 -> bf16, [k][n] -> [n][k])
__global__ __launch_bounds__(256) void prep(
    const void* __restrict__ w0, const void* __restrict__ w1,
    const void* __restrict__ w2, const void* __restrict__ w3,
    u16* t0, u16* t1, u16* t2, u16* t3, const int f32f){
  __shared__ u16 tile[32][33];
  int z = blockIdx.z;
  int tid = threadIdx.x;
  bool f32 = f32f != 0;
  const void* in = z==0?w0 : z==1?w1 : z==2?w2 : w3;
  u16* out = z==0?t0 : z==1?t1 : z==2?t2 : t3;
  int tx = tid & 31, ty = tid >> 5;
  int c  = blockIdx.x*32 + tx;
  int r0 = blockIdx.y*32;
  for (int i=ty;i<32;i+=8){
    long off = (long)(r0+i)*DM + c;
    tile[i][tx] = f32 ? f2bf(((const float*)in)[off]) : ((const u16*)in)[off];
  }
  __syncthreads();
  int rr = r0 + tx, cb = blockIdx.x*32;
  for (int i=ty;i<32;i+=8) out[(long)(cb+i)*DM + rr] = tile[tx][i];
}

// Fused QKV projection: z=0 -> Q (scaled by CS), z=1 -> K, z=2 -> V (written
// transposed per head with in-tile key permutation sigma:
//   n = rt*16 + q*4 + r  ->  p = 32*(rt>>1) + 8*q + 4*(rt&1) + r
// matching the attention kernel's in-register P fragment order.
// 128x128 tile, 4 waves, BK=32, double-buffered LDS, counted vmcnt, pair-line
// XOR swizzle (phys_slot = log_slot ^ (line_or_row & 7); global_load_lds
// writes linearly so the SOURCE lane addresses are pre-permuted, and reads
// apply the same XOR -> ds phases hit every bank group 2x = conflict-free).
// AF32=0: A is bf16, DMA-staged exactly like B (proven R7 path).
// AF32=1: A is f32, DMA-staged AS F32 into a 32KB swizzled LDS tile
//         (4 dma16/wave/buffer, per-lane pre-permuted source); fragments are
//         converted f32->bf16 at LDS-read time (2x float4 + 4 pk2 per frag).
//         No global-load latency in the loop (unlike the failed R3/R8
//         reg-staged variants); removes the separate convert pass entirely.
template<int AF32>
__global__ __launch_bounds__(256) void gemm_qkv(
    const void* __restrict__ A0, const void* __restrict__ A1, const void* __restrict__ A2,
    const u16* __restrict__ W0, const u16* __restrict__ W1, const u16* __restrict__ W2,
    const void* __restrict__ bv0, const void* __restrict__ bv1, const void* __restrict__ bv2,
    u16* C0, u16* C1, u16* C2, const int f32f){
  constexpr int ABYTES = AF32 ? 32768 : 16384;
  __shared__ __align__(16) char AsRaw[ABYTES];
  __shared__ __align__(16) u16 Bs[2][128*32];
  int z = blockIdx.z;
  const void* A  = z==0?A0 : z==1?A1 : A2;
  const u16* BT  = z==0?W0 : z==1?W1 : W2;
  const void* bias = z==0?bv0 : z==1?bv1 : bv2;
  u16* C = z==0?C0 : z==1?C1 : C2;
  const bool bF32 = (f32f != 0);
  int tid = threadIdx.x;
  int by = blockIdx.x, bx = blockIdx.y;
  int lane = tid & 63, w = tid >> 6;
  int t = lane & 15, q = lane >> 4;
  int wr = w >> 1, wc = w & 1;
  f32x4 acc[4][4];
  #pragma unroll
  for(int i=0;i<4;i++) for(int j=0;j<4;j++) for(int k=0;k<4;k++) acc[i][j][k]=0.f;

  // B staging source swizzle (shared by both paths):
  // lane -> line=lane>>3, phys slot=lane&7, logical slot sl=(lane&7)^line;
  // row = 2*line + sl>>2, col16 = sl&3.
  int sl = (lane & 7) ^ (lane >> 3);
  int srow = ((lane >> 3) << 1) + (sl >> 2);
  const u16* gB = BT + ((long)(bx*128 + w*32 + srow)*DM + (sl&3)*8);
  const int lbB = w*1024;                 // wave stripe base (u16)
  // swizzled b128 read offset for fragment row R0+t, col16 q (u16 units):
  int rdo = ((t>>1)<<6) + (((((t&1)<<2) | q) ^ (t>>1)) << 3);

  if constexpr (AF32){
    // ---- f32-A-in-LDS path ----
    float* Af = (float*)AsRaw;            // [2][4096] floats (16KB per buffer)
    // A staging: wave stages its 32 rows x 32 k (f32) = 4 dma16.
    // dma i, lane l: LDS float idx = w*1024 + i*256 + l*4
    //   -> row = i*8 + (l>>3), phys 16B slot = l&7.
    // source logical slot = (l&7) ^ (row&7)  (so phys p holds logical p^row).
    const float* gA[4];
    #pragma unroll
    for (int i=0;i<4;i++){
      int arow = i*8 + (lane>>3);
      int slA  = (lane&7) ^ (arow&7);
      gA[i] = (const float*)A + ((long)(by*128 + w*32 + arow)*DM + slA*4);
    }
    const int lbA = w*1024;               // float units
    const int aro = (t&7);                // read-side slot XOR (row&7 == t&7)

    // prologue: tile 0 -> buf 0
    #pragma unroll
    for (int i=0;i<4;i++) dma16((const u16*)gA[i], (const u16*)(Af + lbA + i*256));
    dma16(gB,         &Bs[0][lbB]);
    dma16(gB + 16*DM, &Bs[0][lbB + 512]);

    for (int k0=0; k0<DM; k0+=32){
      int cur = (k0>>5)&1;
      if (k0+32 < DM){
        #pragma unroll
        for (int i=0;i<4;i++)
          dma16((const u16*)(gA[i] + k0+32), (const u16*)(Af + (cur^1)*4096 + lbA + i*256));
        dma16(gB + k0+32,         &Bs[cur^1][lbB]);
        dma16(gB + k0+32 + 16*DM, &Bs[cur^1][lbB + 512]);
        asm volatile("s_waitcnt vmcnt(6)" ::: "memory");   // tile k0 landed
      } else {
        asm volatile("s_waitcnt vmcnt(0)" ::: "memory");
      }
      __builtin_amdgcn_s_barrier();
      union { bf16x8 f; u32 u[4]; } af[4];
      bf16x8 bfr[4];
      const float* Ac = Af + cur*4096;
      #pragma unroll
      for (int rt=0;rt<4;rt++){
        int R = wr*64 + rt*16 + t;
        const float* pr = Ac + R*32;
        float4 x0 = *(const float4*)(pr + (((2*q  ) ^ aro) << 2));
        float4 x1 = *(const float4*)(pr + (((2*q+1) ^ aro) << 2));
        af[rt].u[0] = pk2(x0.x,x0.y); af[rt].u[1] = pk2(x0.z,x0.w);
        af[rt].u[2] = pk2(x1.x,x1.y); af[rt].u[3] = pk2(x1.z,x1.w);
      }
      const u16* Br = &Bs[cur][wc*2048 + rdo];
      #pragma unroll
      for (int ct=0;ct<4;ct++) bfr[ct] = frag16v(Br + ct*512);
      #pragma unroll
      for (int rt=0;rt<4;rt++)
        #pragma unroll
        for (int ct=0;ct<4;ct++)
          acc[rt][ct] = __builtin_amdgcn_mfma_f32_16x16x32_bf16(af[rt].f, bfr[ct], acc[rt][ct], 0,0,0);
      __builtin_amdgcn_s_barrier();
    }
  } else {
    // ---- bf16-A DMA path (proven R7 structure) ----
    u16 (*As)[128*32] = (u16(*)[128*32])AsRaw;
    const u16* gA = (const u16*)A + ((long)(by*128 + w*32 + srow)*DM + (sl&3)*8);
    // prologue: tile 0 -> buf 0
    dma16(gA,         &As[0][lbB]);
    dma16(gA + 16*DM, &As[0][lbB + 512]);
    dma16(gB,         &Bs[0][lbB]);
    dma16(gB + 16*DM, &Bs[0][lbB + 512]);
    for (int k0=0; k0<DM; k0+=32){
      int cur = (k0>>5)&1;
      if (k0+32 < DM){
        dma16(gA + k0+32,         &As[cur^1][lbB]);
        dma16(gA + k0+32 + 16*DM, &As[cur^1][lbB + 512]);
        dma16(gB + k0+32,         &Bs[cur^1][lbB]);
        dma16(gB + k0+32 + 16*DM, &Bs[cur^1][lbB + 512]);
        asm volatile("s_waitcnt vmcnt(4)" ::: "memory");   // tile k0 landed
      } else {
        asm volatile("s_waitcnt vmcnt(0)" ::: "memory");
      }
      __builtin_amdgcn_s_barrier();
      bf16x8 af[4], bfr[4];
      const u16* Ar = &As[cur][wr*2048 + rdo];
      const u16* Br = &Bs[cur][wc*2048 + rdo];
      #pragma unroll
      for (int rt=0;rt<4;rt++) af[rt]  = frag16v(Ar + rt*512);
      #pragma unroll
      for (int ct=0;ct<4;ct++) bfr[ct] = frag16v(Br + ct*512);
      #pragma unroll
      for (int rt=0;rt<4;rt++)
        #pragma unroll
        for (int ct=0;ct<4;ct++)
          acc[rt][ct] = __builtin_amdgcn_mfma_f32_16x16x32_bf16(af[rt], bfr[ct], acc[rt][ct], 0,0,0);
      __builtin_amdgcn_s_barrier();
    }
  }

  float scale = (z==0) ? CS : 1.0f;
  #pragma unroll
  for (int ct=0;ct<4;ct++){
    int col = bx*128 + wc*64 + ct*16 + t;
    float bvv = bF32 ? ((const float*)bias)[col] : bf2f(((const u16*)bias)[col]);
    #pragma unroll
    for (int rt=0;rt<4;rt++){
      int row0 = by*128 + wr*64 + rt*16 + q*4;
      if (z == 2){
        int bb = row0 >> 11, s = row0 & 2047;
        long vbase = (long)bb*2097152 + (long)col*2048
                   + (s & ~63) + ((rt>>1)<<5) + (q<<3) + ((rt&1)<<2);
        u32 lo = pk2(acc[rt][ct][0]+bvv, acc[rt][ct][1]+bvv);
        u32 hi = pk2(acc[rt][ct][2]+bvv, acc[rt][ct][3]+bvv);
        *(uint2*)(C + vbase) = make_uint2(lo,hi);
      } else {
        #pragma unroll
        for (int r=0;r<4;r++)
          C[(long)(row0+r)*DM + col] = f2bf((acc[rt][ct][r] + bvv)*scale);
      }
    }
  }
}

// Output projection: A bf16 in ws, both operands DMA-staged, double-buffered,
// same pair-line XOR swizzle.
__global__ __launch_bounds__(256) void gemm_o(const u16* __restrict__ A,
    const u16* __restrict__ BT, const void* __restrict__ bias, void* __restrict__ C,
    const int f32f){
  __shared__ __align__(16) u16 As[2][128*32];
  __shared__ __align__(16) u16 Bs[2][128*32];
  const int f = f32f;
  int tid = threadIdx.x;
  int by = blockIdx.x, bx = blockIdx.y;
  int lane = tid & 63, w = tid >> 6;
  int t = lane & 15, q = lane >> 4;
  int wr = w >> 1, wc = w & 1;
  f32x4 acc[4][4];
  #pragma unroll
  for(int i=0;i<4;i++) for(int j=0;j<4;j++) for(int k=0;k<4;k++) acc[i][j][k]=0.f;

  int sl = (lane & 7) ^ (lane >> 3);
  int srow = ((lane >> 3) << 1) + (sl >> 2);
  const u16* gA = A  + ((long)(by*128 + w*32 + srow)*DM + (sl&3)*8);
  const u16* gB = BT + ((long)(bx*128 + w*32 + srow)*DM + (sl&3)*8);
  const int lb = w*1024;
  int rdo = ((t>>1)<<6) + (((((t&1)<<2) | q) ^ (t>>1)) << 3);
  // prologue: tile 0 -> buf 0
  dma16(gA,         &As[0][lb]);
  dma16(gA + 16*DM, &As[0][lb + 512]);
  dma16(gB,         &Bs[0][lb]);
  dma16(gB + 16*DM, &Bs[0][lb + 512]);
  for (int k0=0; k0<DM; k0+=32){
    int cur = (k0>>5)&1;
    if (k0+32 < DM){
      dma16(gA + k0+32,         &As[cur^1][lb]);
      dma16(gA + k0+32 + 16*DM, &As[cur^1][lb + 512]);
      dma16(gB + k0+32,         &Bs[cur^1][lb]);
      dma16(gB + k0+32 + 16*DM, &Bs[cur^1][lb + 512]);
      asm volatile("s_waitcnt vmcnt(4)" ::: "memory");
    } else {
      asm volatile("s_waitcnt vmcnt(0)" ::: "memory");
    }
    __builtin_amdgcn_s_barrier();
    bf16x8 af[4], bfr[4];
    const u16* Ar = &As[cur][wr*2048 + rdo];
    const u16* Br = &Bs[cur][wc*2048 + rdo];
    #pragma unroll
    for (int rt=0;rt<4;rt++) af[rt]  = frag16v(Ar + rt*512);
    #pragma unroll
    for (int ct=0;ct<4;ct++) bfr[ct] = frag16v(Br + ct*512);
    #pragma unroll
    for (int rt=0;rt<4;rt++)
      #pragma unroll
      for (int ct=0;ct<4;ct++)
        acc[rt][ct] = __builtin_amdgcn_mfma_f32_16x16x32_bf16(af[rt], bfr[ct], acc[rt][ct], 0,0,0);
    __builtin_amdgcn_s_barrier();
  }
  #pragma unroll
  for (int ct=0;ct<4;ct++){
    int col = bx*128 + wc*64 + ct*16 + t;
    float bvv = f ? ((const float*)bias)[col] : bf2f(((const u16*)bias)[col]);
    #pragma unroll
    for (int rt=0;rt<4;rt++){
      int row0 = by*128 + wr*64 + rt*16 + q*4;
      #pragma unroll
      for (int r=0;r<4;r++){
        long idx = (long)(row0+r)*DM + col;
        float v = acc[rt][ct][r] + bvv;
        if (f) ((float*)C)[idx] = v;
        else   ((u16*)C)[idx]  = f2bf(v);
      }
    }
  }
}

// Flash attention v5b (R2/R7 schedule + zero-C first MFMA).
// Swapped QK^T: mfma(K, Q) puts P[qrow=t][key=16c+4q+r] lane-local; V is
// stored (by gemm_qkv) with the sigma key-permutation so PV A-fragments are
// built entirely in-register (cvt_pk only): NO P LDS round-trip. Row sums
// via a constant ones-column B-fragment MFMA (o4). K/V double-buffered in
// stride-64 LDS via global_load_lds with XOR-pre-swizzled source. Two
// barriers/iter; prefetch issued before vmcnt(4) (race-free: the
// end-of-iteration barrier orders all reads of the target buffer before any
// wave's next-iteration prefetch). LDS=32KB -> 4 blocks/CU (grid 1024).
__global__ __launch_bounds__(256,4) void attn5(const u16* __restrict__ Q,
    const u16* __restrict__ Kb, const u16* __restrict__ Vt, u16* __restrict__ O){
  __shared__ __align__(16) u16 Ks[2][4096];   // [buf][64 s-rows][64 d], swizzled
  __shared__ __align__(16) u16 Vs[2][4096];   // [buf][64 dh-rows][64 kpos], swizzled
  int tid = threadIdx.x;
  int bid = blockIdx.x;
  int qt = bid >> 6;
  int s6 = bid & 63;
  int bh = (s6 & 7)*8 + (s6 >> 3);   // all 16 qt-blocks of a bh share bid%8 -> same XCD
  int b = bh >> 4, h = bh & 15;
  int lane = tid & 63, w = tid >> 6;
  int t = lane & 15, q = lane >> 4;

  // Q fragments (B-operand): col = qrow = t (+rt*16), k = d = ks*32 + q*8 ..
  const u16* Qbase = Q + ((long)(b*S_ + qt*128 + w*32 + t)*DM + h*DH + q*8);
  bf16x8 qf[2][2];
  qf[0][0] = frag16v(Qbase);
  qf[0][1] = frag16v(Qbase + 32);
  qf[1][0] = frag16v(Qbase + 16*DM);
  qf[1][1] = frag16v(Qbase + 16*DM + 32);

  // DMA chunk mapping: chunk c = tid; row = c>>3, 16B-slot = c&7,
  // global source slot pre-swizzled by row&7 so linear LDS + XOR read works.
  int r0 = tid >> 3;
  int cb = ((tid & 7) * 16) ^ ((r0 & 7) << 4);
  const char* gK = (const char*)Kb + (((long)(b*S_ + r0)*DM + h*DH) << 1) + cb;
  const char* gV = (const char*)Vt + ((((long)bh << 17) + ((long)r0 << 11)) << 1) + cb;
  const long gK1 = ((long)32*DM) << 1;     // +32 s-rows
  const long gV1 = ((long)32*S_) << 1;     // +32 dh-rows
  const int ld0 = w*512, ld1 = 2048 + w*512;   // wave-uniform LDS bases (u16)

  f32x4 o[2][4];
  #pragma unroll
  for (int i=0;i<2;i++) for (int j=0;j<4;j++) for (int k=0;k<4;k++) o[i][j][k]=0.f;
  f32x4 o4[2];
  #pragma unroll
  for (int i=0;i<2;i++) for (int k=0;k<4;k++) o4[i][k]=0.f;

  const f32x4 z4 = {0.f, 0.f, 0.f, 0.f};   // loop-invariant zero C operand

  // ones B-fragment: column 0 all-ones -> o4 row-sums
  union { bf16x8 f; u32 u[4]; } vone;
  { u32 ovv = (t==0) ? 0x3F803F80u : 0u;
    vone.u[0]=ovv; vone.u[1]=ovv; vone.u[2]=ovv; vone.u[3]=ovv; }

  const int xorv = (t & 7) << 4;   // read-side byte XOR (row&7 == t&7 for all frags)

  // prologue: stage tile 0 into buf 0
  dma16((const u16*)(gK),       &Ks[0][ld0]);
  dma16((const u16*)(gK + gK1), &Ks[0][ld1]);
  dma16((const u16*)(gV),       &Vs[0][ld0]);
  dma16((const u16*)(gV + gV1), &Vs[0][ld1]);

  for (int kt=0; kt<32; kt++){
    int cur = kt & 1;
    if (kt < 31){
      long ko = ((long)(kt+1)*64*DM) << 1;   // K advances 64 s-rows
      long vo = (long)(kt+1) << 7;           // V advances 64 key-positions (128 B)
      dma16((const u16*)(gK + ko),       &Ks[cur^1][ld0]);
      dma16((const u16*)(gK + ko + gK1), &Ks[cur^1][ld1]);
      dma16((const u16*)(gV + vo),       &Vs[cur^1][ld0]);
      dma16((const u16*)(gV + vo + gV1), &Vs[cur^1][ld1]);
      asm volatile("s_waitcnt vmcnt(4)" ::: "memory");   // tile kt ready, kt+1 in flight
    } else {
      asm volatile("s_waitcnt vmcnt(0)" ::: "memory");
    }
    __builtin_amdgcn_s_barrier();

    const u16* Kc = Ks[cur];
    const u16* Vc = Vs[cur];

    // QK^T swapped: mfma(K, Q) -> lane (t,q) holds P[qrow=t][key=16c+4q+r]
    // ks=0 uses z4 as C-in (no per-iteration sacc zeroing).
    f32x4 sacc[2][4];
    {
      int off = ((q*16) ^ xorv) >> 1;
      bf16x8 k0 = frag16v(Kc + (t     )*64 + off);
      bf16x8 k1 = frag16v(Kc + (16 + t)*64 + off);
      bf16x8 k2 = frag16v(Kc + (32 + t)*64 + off);
      bf16x8 k3 = frag16v(Kc + (48 + t)*64 + off);
      __builtin_amdgcn_s_setprio(1);
      #pragma unroll
      for (int rt=0; rt<2; rt++){
        sacc[rt][0] = __builtin_amdgcn_mfma_f32_16x16x32_bf16(k0, qf[rt][0], z4, 0,0,0);
        sacc[rt][1] = __builtin_amdgcn_mfma_f32_16x16x32_bf16(k1, qf[rt][0], z4, 0,0,0);
        sacc[rt][2] = __builtin_amdgcn_mfma_f32_16x16x32_bf16(k2, qf[rt][0], z4, 0,0,0);
        sacc[rt][3] = __builtin_amdgcn_mfma_f32_16x16x32_bf16(k3, qf[rt][0], z4, 0,0,0);
      }
      __builtin_amdgcn_s_setprio(0);
    }
    {
      int off = ((64 + q*16) ^ xorv) >> 1;
      bf16x8 k0 = frag16v(Kc + (t     )*64 + off);
      bf16x8 k1 = frag16v(Kc + (16 + t)*64 + off);
      bf16x8 k2 = frag16v(Kc + (32 + t)*64 + off);
      bf16x8 k3 = frag16v(Kc + (48 + t)*64 + off);
      __builtin_amdgcn_s_setprio(1);
      #pragma unroll
      for (int rt=0; rt<2; rt++){
        sacc[rt][0] = __builtin_amdgcn_mfma_f32_16x16x32_bf16(k0, qf[rt][1], sacc[rt][0],0,0,0);
        sacc[rt][1] = __builtin_amdgcn_mfma_f32_16x16x32_bf16(k1, qf[rt][1], sacc[rt][1],0,0,0);
        sacc[rt][2] = __builtin_amdgcn_mfma_f32_16x16x32_bf16(k2, qf[rt][1], sacc[rt][2],0,0,0);
        sacc[rt][3] = __builtin_amdgcn_mfma_f32_16x16x32_bf16(k3, qf[rt][1], sacc[rt][3],0,0,0);
      }
      __builtin_amdgcn_s_setprio(0);
    }

    // softmax (no max-sub) + in-register P->A-fragment pack:
    // af[rt][ks] element e = exp2(sacc[rt][2ks + (e>>2)][e&3])
    union { bf16x8 f; u32 u[4]; } af[2][2];
    #pragma unroll
    for (int rt=0; rt<2; rt++){
      float ev[4][4];
      #pragma unroll
      for (int c=0; c<4; c++)
        #pragma unroll
        for (int r=0; r<4; r++) ev[c][r] = EXP2F(sacc[rt][c][r]);
      #pragma unroll
      for (int ks=0; ks<2; ks++){
        af[rt][ks].u[0] = pk2(ev[2*ks  ][0], ev[2*ks  ][1]);
        af[rt][ks].u[1] = pk2(ev[2*ks  ][2], ev[2*ks  ][3]);
        af[rt][ks].u[2] = pk2(ev[2*ks+1][0], ev[2*ks+1][1]);
        af[rt][ks].u[3] = pk2(ev[2*ks+1][2], ev[2*ks+1][3]);
      }
    }

    // PV: O += P * V ; V columns are sigma-permuted to match af's key order.
    #pragma unroll
    for (int ks=0; ks<2; ks++){
      int off = ((ks*64 + q*16) ^ xorv) >> 1;
      bf16x8 v0 = frag16v(Vc + (t     )*64 + off);
      bf16x8 v1 = frag16v(Vc + (16 + t)*64 + off);
      bf16x8 v2 = frag16v(Vc + (32 + t)*64 + off);
      bf16x8 v3 = frag16v(Vc + (48 + t)*64 + off);
      __builtin_amdgcn_s_setprio(1);
      #pragma unroll
      for (int rt=0; rt<2; rt++){
        o[rt][0] = __builtin_amdgcn_mfma_f32_16x16x32_bf16(af[rt][ks].f, v0, o[rt][0],0,0,0);
        o[rt][1] = __builtin_amdgcn_mfma_f32_16x16x32_bf16(af[rt][ks].f, v1, o[rt][1],0,0,0);
        o[rt][2] = __builtin_amdgcn_mfma_f32_16x16x32_bf16(af[rt][ks].f, v2, o[rt][2],0,0,0);
        o[rt][3] = __builtin_amdgcn_mfma_f32_16x16x32_bf16(af[rt][ks].f, v3, o[rt][3],0,0,0);
        o4[rt]   = __builtin_amdgcn_mfma_f32_16x16x32_bf16(af[rt][ks].f, vone.f, o4[rt],0,0,0);
      }
      __builtin_amdgcn_s_setprio(0);
    }
    __builtin_amdgcn_s_barrier();
  }

  // epilogue: l = row sum (held at lanes t==0 of same q), broadcast, normalize
  #pragma unroll
  for (int rt=0; rt<2; rt++){
    #pragma unroll
    for (int r=0; r<4; r++){
      float l = __shfl(o4[rt][r], lane & 48);
      float inv = 1.f / l;
      int row = qt*128 + w*32 + rt*16 + q*4 + r;
      #pragma unroll
      for (int ct=0; ct<4; ct++)
        O[(long)(b*S_ + row)*DM + h*DH + ct*16 + t] = f2bf(o[rt][ct][r] * inv);
    }
  }
}

extern "C" void kernel_launch(void* const* d_in, const int* in_sizes, int n_in,
                              void* d_out, int out_size, void* d_ws, size_t ws_size,
                              hipStream_t stream){
  (void)n_in; (void)out_size; (void)ws_size;
  const void* xq = d_in[0];
  const void* xk = d_in[1];
  const void* xv = d_in[2];
  const void* Wq = d_in[3];
  const void* bq = d_in[4];
  const void* Wk = d_in[5];
  const void* bk = d_in[6];
  const void* Wv = d_in[7];
  const void* bv = d_in[8];
  const void* Wo = d_in[9];
  const void* bo = d_in[10];

  // dtype from host-side size: bf16 iff input 0 is exactly NT*2 bytes.
  const long NT = (long)BS*DM;                    // 8,388,608 elements
  int f32f = 1;
  if (in_sizes && in_sizes[0] == (int)(NT*2)) f32f = 0;

  u16* base = (u16*)((char*)d_ws + 256);
  u16* Qb  = base;                                // Q (scaled), later attention O
  u16* Kbf = base + NT;
  u16* Vt  = base + 2*NT;                         // [b*16+h][64][2048], sigma-permuted
  u16* WqT = base + 3*NT;
  u16* WkT = WqT + (long)DM*DM;
  u16* WvT = WkT + (long)DM*DM;
  u16* WoT = WvT + (long)DM*DM;

  dim3 gb(256,1,1);
  prep<<<dim3(32,32,4), gb, 0, stream>>>(Wq, Wk, Wv, Wo,
      WqT, WkT, WvT, WoT, f32f);

  if (f32f){
    gemm_qkv<1><<<dim3(64,8,3), gb, 0, stream>>>(xq, xk, xv,
        WqT, WkT, WvT, bq, bk, bv, Qb, Kbf, Vt, f32f);
  } else {
    gemm_qkv<0><<<dim3(64,8,3), gb, 0, stream>>>(xq, xk, xv,
        WqT, WkT, WvT, bq, bk, bv, Qb, Kbf, Vt, f32f);
  }

  attn5<<<dim3(1024,1,1), gb, 0, stream>>>(Qb, Kbf, Vt, Qb /* O reuses Q */);

  gemm_o<<<dim3(64,8,1), gb, 0, stream>>>(Qb, WoT, bo, d_out, f32f);
}

// Round 11
// 347.699 us; speedup vs baseline: 1.1327x; 1.1327x over previous
//
#include <hip/hip_runtime.h>

typedef unsigned short u16;
typedef unsigned int   u32;
typedef unsigned long long u64;
typedef __attribute__((ext_vector_type(8))) short bf16x8;
typedef __attribute__((ext_vector_type(4))) float f32x4;

#define S_  2048
#define DH  64
#define DM  1024
#define BS  8192
#define CS  0.18033688011112042f   // 0.125 * log2(e)

static __device__ __forceinline__ float bf2f(u16 v){ return __uint_as_float(((u32)v)<<16); }
static __device__ __forceinline__ u16 f2bf(float f){
  u32 x = __float_as_uint(f);
  return (u16)((x + 0x7fffu + ((x>>16)&1u)) >> 16);   // RNE
}
#if __has_builtin(__builtin_amdgcn_cvt_pk_bf16_f32)
static __device__ __forceinline__ u32 pk2(float x, float y){
  typedef __attribute__((ext_vector_type(2))) __bf16 bf2v;
  union { bf2v v; u32 u; } c; c.v = __builtin_amdgcn_cvt_pk_bf16_f32(x, y); return c.u;
}
#else
static __device__ __forceinline__ u32 pk2(float x, float y){
  return (u32)f2bf(x) | ((u32)f2bf(y) << 16);
}
#endif
#if __has_builtin(__builtin_amdgcn_exp2f)
#define EXP2F(x) __builtin_amdgcn_exp2f(x)
#else
#define EXP2F(x) exp2f(x)
#endif

// async global->LDS, 16B/lane; LDS dest = wave-uniform base + lane*16
static __device__ __forceinline__ void dma16(const u16* g, const u16* l){
  __builtin_amdgcn_global_load_lds(
      (const __attribute__((address_space(1))) u32*)(u64)(uintptr_t)g,
      (__attribute__((address_space(3))) u32*)(u32)(u64)(uintptr_t)l, 16, 0, 0);
}

static __device__ __forceinline__ bf16x8 lds_frag(const u16* p){
  union { bf16x8 f; uint2 u[2]; } w;
  w.u[0] = *(const uint2*)(p);
  w.u[1] = *(const uint2*)(p+4);
  return w.f;
}
// 16B-aligned fragment load (single ds_read_b128)
static __device__ __forceinline__ bf16x8 frag16v(const u16* p){
  union { bf16x8 f; uint4 u; } w;
  w.u = *(const uint4*)p;
  return w.f;
}
static __device__ __forceinline__ void stage16_bf(const u16* __restrict__ g, u16* s){
  uint4 a = *(const uint4*)g;
  uint4 b = *(const uint4*)(g+8);
  *(uint2*)(s+0)  = make_uint2(a.x,a.y);
  *(uint2*)(s+4)  = make_uint2(a.z,a.w);
  *(uint2*)(s+8)  = make_uint2(b.x,b.y);
  *(uint2*)(s+12) = make_uint2(b.z,b.w);
}
static __device__ __forceinline__ void stage16_f32(const float* __restrict__ g, u16* s){
  float4 a0 = ((const float4*)g)[0];
  float4 a1 = ((const float4*)g)[1];
  float4 a2 = ((const float4*)g)[2];
  float4 a3 = ((const float4*)g)[3];
  *(uint2*)(s+0)  = make_uint2(pk2(a0.x,a0.y), pk2(a0.z,a0.w));
  *(uint2*)(s+4)  = make_uint2(pk2(a1.x,a1.y), pk2(a1.z,a1.w));
  *(uint2*)(s+8)  = make_uint2(pk2(a2.x,a2.y), pk2(a2.z,a2.w));
  *(uint2*)(s+12) = make_uint2(pk2(a3.x,a3.y), pk2(a3.z,a3.w));
}

// prep: z=0..3 -> weight transpose (f32/bf16 -> bf16, [k][n] -> [n][k]);
//       z=4..6 -> activation f32->bf16 convert (skipped when input is bf16).
// NOTE (session lesson, R3/R6/R8/R10): keeping the activation convert as a
// separate bandwidth-bound pass feeding global_load_lds-staged GEMMs beat
// every in-GEMM conversion variant by 70-90 us. Do not re-fuse.
__global__ __launch_bounds__(256) void prep(
    const void* __restrict__ w0, const void* __restrict__ w1,
    const void* __restrict__ w2, const void* __restrict__ w3,
    u16* t0, u16* t1, u16* t2, u16* t3,
    const void* __restrict__ a0, const void* __restrict__ a1,
    const void* __restrict__ a2,
    u16* c0, u16* c1, u16* c2, const int f32f){
  __shared__ u16 tile[32][33];
  int z = blockIdx.z;
  int tid = threadIdx.x;
  bool f32 = f32f != 0;
  if (z < 4){
    const void* in = z==0?w0 : z==1?w1 : z==2?w2 : w3;
    u16* out = z==0?t0 : z==1?t1 : z==2?t2 : t3;
    int tx = tid & 31, ty = tid >> 5;
    int c  = blockIdx.x*32 + tx;
    int r0 = blockIdx.y*32;
    for (int i=ty;i<32;i+=8){
      long off = (long)(r0+i)*DM + c;
      tile[i][tx] = f32 ? f2bf(((const float*)in)[off]) : ((const u16*)in)[off];
    }
    __syncthreads();
    int rr = r0 + tx, cb = blockIdx.x*32;
    for (int i=ty;i<32;i+=8) out[(long)(cb+i)*DM + rr] = tile[tx][i];
  } else {
    if (!f32) return;
    const void* in = z==4?a0 : z==5?a1 : a2;
    u16* out = z==4?c0 : z==5?c1 : c2;
    long lb = (long)blockIdx.y*32 + blockIdx.x;     // 0..1023
    long base = (lb*256 + tid)*8;
    #pragma unroll
    for (int it=0; it<4; it++){
      long i = base + (long)it*2097152;
      const float4* p = (const float4*)((const float*)in + i);
      float4 x = p[0], y = p[1];
      *(uint4*)(out + i) = make_uint4(pk2(x.x,x.y), pk2(x.z,x.w), pk2(y.x,y.y), pk2(y.z,y.w));
    }
  }
}

// Fused QKV projection: z=0 -> Q (scaled by CS), z=1 -> K, z=2 -> V (written
// transposed per head with in-tile key permutation sigma:
//   n = rt*16 + q*4 + r  ->  p = 32*(rt>>1) + 8*q + 4*(rt&1) + r
// matching the attention kernel's in-register P fragment order.
// 128x128 tile, 4 waves, BK=32. ADMA=1: A is bf16, both operands DMA-staged
// with double-buffered LDS + counted vmcnt (2-phase pipeline) and a
// pair-line XOR swizzle: the 128x32 tile is viewed as 64 lines of 128B
// (2 rows each); phys_slot = log_slot ^ (line&7). global_load_lds writes
// linearly, so the SOURCE address is pre-permuted per lane and the ds_read
// applies the same XOR -> each 16-lane read phase hits every 4-bank group
// exactly twice (minimal). Measured conflict-free (R8: 0 conflicts).
template<int ADMA>
__global__ __launch_bounds__(256) void gemm_qkv(
    const void* __restrict__ A0, const void* __restrict__ A1, const void* __restrict__ A2,
    const u16* __restrict__ W0, const u16* __restrict__ W1, const u16* __restrict__ W2,
    const void* __restrict__ bv0, const void* __restrict__ bv1, const void* __restrict__ bv2,
    u16* C0, u16* C1, u16* C2, const int f32f){
  constexpr int AST = ADMA ? 32 : 36;
  constexpr int NB  = ADMA ? 2 : 1;
  __shared__ __align__(16) u16 As[NB][128*AST];
  __shared__ __align__(16) u16 Bs[NB][128*32];
  int z = blockIdx.z;
  const void* A  = z==0?A0 : z==1?A1 : A2;
  const u16* BT  = z==0?W0 : z==1?W1 : W2;
  const void* bias = z==0?bv0 : z==1?bv1 : bv2;
  u16* C = z==0?C0 : z==1?C1 : C2;
  const bool aF32 = (!ADMA) && (f32f != 0);
  const bool bF32 = (f32f != 0);
  int tid = threadIdx.x;
  int by = blockIdx.x, bx = blockIdx.y;
  int lane = tid & 63, w = tid >> 6;
  int t = lane & 15, q = lane >> 4;
  int wr = w >> 1, wc = w & 1;
  f32x4 acc[4][4];
  #pragma unroll
  for(int i=0;i<4;i++) for(int j=0;j<4;j++) for(int k=0;k<4;k++) acc[i][j][k]=0.f;

  if constexpr (ADMA){
    // swizzled staging source: lane -> line=lane>>3, phys slot=lane&7,
    // logical slot sl = (lane&7)^line; row = 2*line + sl>>2, col16 = sl&3.
    int sl = (lane & 7) ^ (lane >> 3);
    int srow = ((lane >> 3) << 1) + (sl >> 2);
    const u16* gA = (const u16*)A + ((long)(by*128 + w*32 + srow)*DM + (sl&3)*8);
    const u16* gB = BT            + ((long)(bx*128 + w*32 + srow)*DM + (sl&3)*8);
    const int lb = w*1024;                  // wave stripe base (u16)
    // swizzled read offset for fragment row R0+t, col16 q:
    int rdo = ((t>>1)<<6) + (((((t&1)<<2) | q) ^ (t>>1)) << 3);
    // prologue: tile 0 -> buf 0
    dma16(gA,         &As[0][lb]);
    dma16(gA + 16*DM, &As[0][lb + 512]);
    dma16(gB,         &Bs[0][lb]);
    dma16(gB + 16*DM, &Bs[0][lb + 512]);
    for (int k0=0; k0<DM; k0+=32){
      int cur = (k0>>5)&1;
      if (k0+32 < DM){
        dma16(gA + k0+32,         &As[cur^1][lb]);
        dma16(gA + k0+32 + 16*DM, &As[cur^1][lb + 512]);
        dma16(gB + k0+32,         &Bs[cur^1][lb]);
        dma16(gB + k0+32 + 16*DM, &Bs[cur^1][lb + 512]);
        asm volatile("s_waitcnt vmcnt(4)" ::: "memory");   // tile k0 landed
      } else {
        asm volatile("s_waitcnt vmcnt(0)" ::: "memory");
      }
      __builtin_amdgcn_s_barrier();
      bf16x8 af[4], bfr[4];
      const u16* Ar = &As[cur][wr*2048 + rdo];
      const u16* Br = &Bs[cur][wc*2048 + rdo];
      #pragma unroll
      for (int rt=0;rt<4;rt++) af[rt]  = frag16v(Ar + rt*512);
      #pragma unroll
      for (int ct=0;ct<4;ct++) bfr[ct] = frag16v(Br + ct*512);
      #pragma unroll
      for (int rt=0;rt<4;rt++)
        #pragma unroll
        for (int ct=0;ct<4;ct++)
          acc[rt][ct] = __builtin_amdgcn_mfma_f32_16x16x32_bf16(af[rt], bfr[ct], acc[rt][ct], 0,0,0);
      __builtin_amdgcn_s_barrier();
    }
  } else {
    const u16* gB = BT + ((long)(bx*128 + w*32 + (lane>>2))*DM + (lane&3)*8);
    long aoff = (long)(by*128 + (tid>>1))*DM + (tid&1)*16;
    const u16* ArdB = &As[0][(wr*64 + t)*AST + q*8];
    const u16* BrdB = &Bs[0][(wc*64 + t)*32  + q*8];
    for (int k0=0; k0<DM; k0+=32){
      dma16(gB + k0,         &Bs[0][w*1024]);
      dma16(gB + 16*DM + k0, &Bs[0][w*1024 + 512]);
      u16* AsW = &As[0][(tid>>1)*36 + (tid&1)*16];
      if (aF32) stage16_f32((const float*)A + aoff + k0, AsW);
      else      stage16_bf ((const u16*)A  + aoff + k0, AsW);
      __syncthreads();
      bf16x8 af[4], bfr[4];
      #pragma unroll
      for (int rt=0;rt<4;rt++) af[rt]  = lds_frag(ArdB + rt*16*AST);
      #pragma unroll
      for (int ct=0;ct<4;ct++) bfr[ct] = lds_frag(BrdB + ct*16*32);
      #pragma unroll
      for (int rt=0;rt<4;rt++)
        #pragma unroll
        for (int ct=0;ct<4;ct++)
          acc[rt][ct] = __builtin_amdgcn_mfma_f32_16x16x32_bf16(af[rt], bfr[ct], acc[rt][ct], 0,0,0);
      __syncthreads();
    }
  }

  float scale = (z==0) ? CS : 1.0f;
  #pragma unroll
  for (int ct=0;ct<4;ct++){
    int col = bx*128 + wc*64 + ct*16 + t;
    float bvv = bF32 ? ((const float*)bias)[col] : bf2f(((const u16*)bias)[col]);
    #pragma unroll
    for (int rt=0;rt<4;rt++){
      int row0 = by*128 + wr*64 + rt*16 + q*4;
      if (z == 2){
        int bb = row0 >> 11, s = row0 & 2047;
        long vbase = (long)bb*2097152 + (long)col*2048
                   + (s & ~63) + ((rt>>1)<<5) + (q<<3) + ((rt&1)<<2);
        u32 lo = pk2(acc[rt][ct][0]+bvv, acc[rt][ct][1]+bvv);
        u32 hi = pk2(acc[rt][ct][2]+bvv, acc[rt][ct][3]+bvv);
        *(uint2*)(C + vbase) = make_uint2(lo,hi);
      } else {
        #pragma unroll
        for (int r=0;r<4;r++)
          C[(long)(row0+r)*DM + col] = f2bf((acc[rt][ct][r] + bvv)*scale);
      }
    }
  }
}

// Output projection: A bf16 in ws, both operands DMA-staged, double-buffered,
// same pair-line XOR swizzle as gemm_qkv<1>.
__global__ __launch_bounds__(256) void gemm_o(const u16* __restrict__ A,
    const u16* __restrict__ BT, const void* __restrict__ bias, void* __restrict__ C,
    const int f32f){
  __shared__ __align__(16) u16 As[2][128*32];
  __shared__ __align__(16) u16 Bs[2][128*32];
  const int f = f32f;
  int tid = threadIdx.x;
  int by = blockIdx.x, bx = blockIdx.y;
  int lane = tid & 63, w = tid >> 6;
  int t = lane & 15, q = lane >> 4;
  int wr = w >> 1, wc = w & 1;
  f32x4 acc[4][4];
  #pragma unroll
  for(int i=0;i<4;i++) for(int j=0;j<4;j++) for(int k=0;k<4;k++) acc[i][j][k]=0.f;

  int sl = (lane & 7) ^ (lane >> 3);
  int srow = ((lane >> 3) << 1) + (sl >> 2);
  const u16* gA = A  + ((long)(by*128 + w*32 + srow)*DM + (sl&3)*8);
  const u16* gB = BT + ((long)(bx*128 + w*32 + srow)*DM + (sl&3)*8);
  const int lb = w*1024;
  int rdo = ((t>>1)<<6) + (((((t&1)<<2) | q) ^ (t>>1)) << 3);
  // prologue: tile 0 -> buf 0
  dma16(gA,         &As[0][lb]);
  dma16(gA + 16*DM, &As[0][lb + 512]);
  dma16(gB,         &Bs[0][lb]);
  dma16(gB + 16*DM, &Bs[0][lb + 512]);
  for (int k0=0; k0<DM; k0+=32){
    int cur = (k0>>5)&1;
    if (k0+32 < DM){
      dma16(gA + k0+32,         &As[cur^1][lb]);
      dma16(gA + k0+32 + 16*DM, &As[cur^1][lb + 512]);
      dma16(gB + k0+32,         &Bs[cur^1][lb]);
      dma16(gB + k0+32 + 16*DM, &Bs[cur^1][lb + 512]);
      asm volatile("s_waitcnt vmcnt(4)" ::: "memory");
    } else {
      asm volatile("s_waitcnt vmcnt(0)" ::: "memory");
    }
    __builtin_amdgcn_s_barrier();
    bf16x8 af[4], bfr[4];
    const u16* Ar = &As[cur][wr*2048 + rdo];
    const u16* Br = &Bs[cur][wc*2048 + rdo];
    #pragma unroll
    for (int rt=0;rt<4;rt++) af[rt]  = frag16v(Ar + rt*512);
    #pragma unroll
    for (int ct=0;ct<4;ct++) bfr[ct] = frag16v(Br + ct*512);
    #pragma unroll
    for (int rt=0;rt<4;rt++)
      #pragma unroll
      for (int ct=0;ct<4;ct++)
        acc[rt][ct] = __builtin_amdgcn_mfma_f32_16x16x32_bf16(af[rt], bfr[ct], acc[rt][ct], 0,0,0);
    __builtin_amdgcn_s_barrier();
  }
  #pragma unroll
  for (int ct=0;ct<4;ct++){
    int col = bx*128 + wc*64 + ct*16 + t;
    float bvv = f ? ((const float*)bias)[col] : bf2f(((const u16*)bias)[col]);
    #pragma unroll
    for (int rt=0;rt<4;rt++){
      int row0 = by*128 + wr*64 + rt*16 + q*4;
      #pragma unroll
      for (int r=0;r<4;r++){
        long idx = (long)(row0+r)*DM + col;
        float v = acc[rt][ct][r] + bvv;
        if (f) ((float*)C)[idx] = v;
        else   ((u16*)C)[idx]  = f2bf(v);
      }
    }
  }
}

// Flash attention v5b (R2/R7 schedule + zero-C first MFMA).
// Swapped QK^T: mfma(K, Q) puts P[qrow=t][key=16c+4q+r] lane-local; V is
// stored (by gemm_qkv) with the sigma key-permutation so PV A-fragments are
// built entirely in-register (cvt_pk only): NO P LDS round-trip. Row sums
// via a constant ones-column B-fragment MFMA (o4). K/V double-buffered in
// stride-64 LDS via global_load_lds with XOR-pre-swizzled source. Two
// barriers/iter; prefetch issued before vmcnt(4) (race-free: the
// end-of-iteration barrier orders all reads of the target buffer before any
// wave's next-iteration prefetch). LDS=32KB -> 4 blocks/CU (grid 1024).
__global__ __launch_bounds__(256,4) void attn5(const u16* __restrict__ Q,
    const u16* __restrict__ Kb, const u16* __restrict__ Vt, u16* __restrict__ O){
  __shared__ __align__(16) u16 Ks[2][4096];   // [buf][64 s-rows][64 d], swizzled
  __shared__ __align__(16) u16 Vs[2][4096];   // [buf][64 dh-rows][64 kpos], swizzled
  int tid = threadIdx.x;
  int bid = blockIdx.x;
  int qt = bid >> 6;
  int s6 = bid & 63;
  int bh = (s6 & 7)*8 + (s6 >> 3);   // all 16 qt-blocks of a bh share bid%8 -> same XCD
  int b = bh >> 4, h = bh & 15;
  int lane = tid & 63, w = tid >> 6;
  int t = lane & 15, q = lane >> 4;

  // Q fragments (B-operand): col = qrow = t (+rt*16), k = d = ks*32 + q*8 ..
  const u16* Qbase = Q + ((long)(b*S_ + qt*128 + w*32 + t)*DM + h*DH + q*8);
  bf16x8 qf[2][2];
  qf[0][0] = frag16v(Qbase);
  qf[0][1] = frag16v(Qbase + 32);
  qf[1][0] = frag16v(Qbase + 16*DM);
  qf[1][1] = frag16v(Qbase + 16*DM + 32);

  // DMA chunk mapping: chunk c = tid; row = c>>3, 16B-slot = c&7,
  // global source slot pre-swizzled by row&7 so linear LDS + XOR read works.
  int r0 = tid >> 3;
  int cb = ((tid & 7) * 16) ^ ((r0 & 7) << 4);
  const char* gK = (const char*)Kb + (((long)(b*S_ + r0)*DM + h*DH) << 1) + cb;
  const char* gV = (const char*)Vt + ((((long)bh << 17) + ((long)r0 << 11)) << 1) + cb;
  const long gK1 = ((long)32*DM) << 1;     // +32 s-rows
  const long gV1 = ((long)32*S_) << 1;     // +32 dh-rows
  const int ld0 = w*512, ld1 = 2048 + w*512;   // wave-uniform LDS bases (u16)

  f32x4 o[2][4];
  #pragma unroll
  for (int i=0;i<2;i++) for (int j=0;j<4;j++) for (int k=0;k<4;k++) o[i][j][k]=0.f;
  f32x4 o4[2];
  #pragma unroll
  for (int i=0;i<2;i++) for (int k=0;k<4;k++) o4[i][k]=0.f;

  const f32x4 z4 = {0.f, 0.f, 0.f, 0.f};   // loop-invariant zero C operand

  // ones B-fragment: column 0 all-ones -> o4 row-sums
  union { bf16x8 f; u32 u[4]; } vone;
  { u32 ovv = (t==0) ? 0x3F803F80u : 0u;
    vone.u[0]=ovv; vone.u[1]=ovv; vone.u[2]=ovv; vone.u[3]=ovv; }

  const int xorv = (t & 7) << 4;   // read-side byte XOR (row&7 == t&7 for all frags)

  // prologue: stage tile 0 into buf 0
  dma16((const u16*)(gK),       &Ks[0][ld0]);
  dma16((const u16*)(gK + gK1), &Ks[0][ld1]);
  dma16((const u16*)(gV),       &Vs[0][ld0]);
  dma16((const u16*)(gV + gV1), &Vs[0][ld1]);

  for (int kt=0; kt<32; kt++){
    int cur = kt & 1;
    if (kt < 31){
      long ko = ((long)(kt+1)*64*DM) << 1;   // K advances 64 s-rows
      long vo = (long)(kt+1) << 7;           // V advances 64 key-positions (128 B)
      dma16((const u16*)(gK + ko),       &Ks[cur^1][ld0]);
      dma16((const u16*)(gK + ko + gK1), &Ks[cur^1][ld1]);
      dma16((const u16*)(gV + vo),       &Vs[cur^1][ld0]);
      dma16((const u16*)(gV + vo + gV1), &Vs[cur^1][ld1]);
      asm volatile("s_waitcnt vmcnt(4)" ::: "memory");   // tile kt ready, kt+1 in flight
    } else {
      asm volatile("s_waitcnt vmcnt(0)" ::: "memory");
    }
    __builtin_amdgcn_s_barrier();

    const u16* Kc = Ks[cur];
    const u16* Vc = Vs[cur];

    // QK^T swapped: mfma(K, Q) -> lane (t,q) holds P[qrow=t][key=16c+4q+r]
    // ks=0 uses z4 as C-in (no per-iteration sacc zeroing).
    f32x4 sacc[2][4];
    {
      int off = ((q*16) ^ xorv) >> 1;
      bf16x8 k0 = frag16v(Kc + (t     )*64 + off);
      bf16x8 k1 = frag16v(Kc + (16 + t)*64 + off);
      bf16x8 k2 = frag16v(Kc + (32 + t)*64 + off);
      bf16x8 k3 = frag16v(Kc + (48 + t)*64 + off);
      __builtin_amdgcn_s_setprio(1);
      #pragma unroll
      for (int rt=0; rt<2; rt++){
        sacc[rt][0] = __builtin_amdgcn_mfma_f32_16x16x32_bf16(k0, qf[rt][0], z4, 0,0,0);
        sacc[rt][1] = __builtin_amdgcn_mfma_f32_16x16x32_bf16(k1, qf[rt][0], z4, 0,0,0);
        sacc[rt][2] = __builtin_amdgcn_mfma_f32_16x16x32_bf16(k2, qf[rt][0], z4, 0,0,0);
        sacc[rt][3] = __builtin_amdgcn_mfma_f32_16x16x32_bf16(k3, qf[rt][0], z4, 0,0,0);
      }
      __builtin_amdgcn_s_setprio(0);
    }
    {
      int off = ((64 + q*16) ^ xorv) >> 1;
      bf16x8 k0 = frag16v(Kc + (t     )*64 + off);
      bf16x8 k1 = frag16v(Kc + (16 + t)*64 + off);
      bf16x8 k2 = frag16v(Kc + (32 + t)*64 + off);
      bf16x8 k3 = frag16v(Kc + (48 + t)*64 + off);
      __builtin_amdgcn_s_setprio(1);
      #pragma unroll
      for (int rt=0; rt<2; rt++){
        sacc[rt][0] = __builtin_amdgcn_mfma_f32_16x16x32_bf16(k0, qf[rt][1], sacc[rt][0],0,0,0);
        sacc[rt][1] = __builtin_amdgcn_mfma_f32_16x16x32_bf16(k1, qf[rt][1], sacc[rt][1],0,0,0);
        sacc[rt][2] = __builtin_amdgcn_mfma_f32_16x16x32_bf16(k2, qf[rt][1], sacc[rt][2],0,0,0);
        sacc[rt][3] = __builtin_amdgcn_mfma_f32_16x16x32_bf16(k3, qf[rt][1], sacc[rt][3],0,0,0);
      }
      __builtin_amdgcn_s_setprio(0);
    }

    // softmax (no max-sub) + in-register P->A-fragment pack:
    // af[rt][ks] element e = exp2(sacc[rt][2ks + (e>>2)][e&3])
    union { bf16x8 f; u32 u[4]; } af[2][2];
    #pragma unroll
    for (int rt=0; rt<2; rt++){
      float ev[4][4];
      #pragma unroll
      for (int c=0; c<4; c++)
        #pragma unroll
        for (int r=0; r<4; r++) ev[c][r] = EXP2F(sacc[rt][c][r]);
      #pragma unroll
      for (int ks=0; ks<2; ks++){
        af[rt][ks].u[0] = pk2(ev[2*ks  ][0], ev[2*ks  ][1]);
        af[rt][ks].u[1] = pk2(ev[2*ks  ][2], ev[2*ks  ][3]);
        af[rt][ks].u[2] = pk2(ev[2*ks+1][0], ev[2*ks+1][1]);
        af[rt][ks].u[3] = pk2(ev[2*ks+1][2], ev[2*ks+1][3]);
      }
    }

    // PV: O += P * V ; V columns are sigma-permuted to match af's key order.
    #pragma unroll
    for (int ks=0; ks<2; ks++){
      int off = ((ks*64 + q*16) ^ xorv) >> 1;
      bf16x8 v0 = frag16v(Vc + (t     )*64 + off);
      bf16x8 v1 = frag16v(Vc + (16 + t)*64 + off);
      bf16x8 v2 = frag16v(Vc + (32 + t)*64 + off);
      bf16x8 v3 = frag16v(Vc + (48 + t)*64 + off);
      __builtin_amdgcn_s_setprio(1);
      #pragma unroll
      for (int rt=0; rt<2; rt++){
        o[rt][0] = __builtin_amdgcn_mfma_f32_16x16x32_bf16(af[rt][ks].f, v0, o[rt][0],0,0,0);
        o[rt][1] = __builtin_amdgcn_mfma_f32_16x16x32_bf16(af[rt][ks].f, v1, o[rt][1],0,0,0);
        o[rt][2] = __builtin_amdgcn_mfma_f32_16x16x32_bf16(af[rt][ks].f, v2, o[rt][2],0,0,0);
        o[rt][3] = __builtin_amdgcn_mfma_f32_16x16x32_bf16(af[rt][ks].f, v3, o[rt][3],0,0,0);
        o4[rt]   = __builtin_amdgcn_mfma_f32_16x16x32_bf16(af[rt][ks].f, vone.f, o4[rt],0,0,0);
      }
      __builtin_amdgcn_s_setprio(0);
    }
    __builtin_amdgcn_s_barrier();
  }

  // epilogue: l = row sum (held at lanes t==0 of same q), broadcast, normalize
  #pragma unroll
  for (int rt=0; rt<2; rt++){
    #pragma unroll
    for (int r=0; r<4; r++){
      float l = __shfl(o4[rt][r], lane & 48);
      float inv = 1.f / l;
      int row = qt*128 + w*32 + rt*16 + q*4 + r;
      #pragma unroll
      for (int ct=0; ct<4; ct++)
        O[(long)(b*S_ + row)*DM + h*DH + ct*16 + t] = f2bf(o[rt][ct][r] * inv);
    }
  }
}

extern "C" void kernel_launch(void* const* d_in, const int* in_sizes, int n_in,
                              void* d_out, int out_size, void* d_ws, size_t ws_size,
                              hipStream_t stream){
  (void)n_in; (void)out_size;
  const void* xq = d_in[0];
  const void* xk = d_in[1];
  const void* xv = d_in[2];
  const void* Wq = d_in[3];
  const void* bq = d_in[4];
  const void* Wk = d_in[5];
  const void* bk = d_in[6];
  const void* Wv = d_in[7];
  const void* bv = d_in[8];
  const void* Wo = d_in[9];
  const void* bo = d_in[10];

  // dtype from host-side size: bf16 iff input 0 is exactly NT*2 bytes.
  const long NT = (long)BS*DM;                    // 8,388,608 elements
  int f32f = 1;
  if (in_sizes && in_sizes[0] == (int)(NT*2)) f32f = 0;

  u16* base = (u16*)((char*)d_ws + 256);
  u16* Qb  = base;                                // Q (scaled), later attention O
  u16* Kbf = base + NT;
  u16* Vt  = base + 2*NT;                         // [b*16+h][64][2048], sigma-permuted
  u16* WqT = base + 3*NT;
  u16* WkT = WqT + (long)DM*DM;
  u16* WvT = WkT + (long)DM*DM;
  u16* WoT = WvT + (long)DM*DM;
  u16* Xc0 = WoT + (long)DM*DM;                   // bf16-converted activations
  u16* Xc1 = Xc0 + NT;
  u16* Xc2 = Xc1 + NT;
  size_t need_pre = 256 + (size_t)(6*NT + 4*(long)DM*DM)*2;   // ~109 MB
  bool pre = ws_size >= need_pre;

  dim3 gb(256,1,1);
  int nz = (pre && f32f) ? 7 : 4;
  prep<<<dim3(32,32,nz), gb, 0, stream>>>(Wq, Wk, Wv, Wo,
      WqT, WkT, WvT, WoT, xq, xk, xv, Xc0, Xc1, Xc2, f32f);

  if (pre){
    const void* Aq = f32f ? (const void*)Xc0 : xq;
    const void* Ak = f32f ? (const void*)Xc1 : xk;
    const void* Av = f32f ? (const void*)Xc2 : xv;
    gemm_qkv<1><<<dim3(64,8,3), gb, 0, stream>>>(Aq, Ak, Av,
        WqT, WkT, WvT, bq, bk, bv, Qb, Kbf, Vt, f32f);
  } else {
    gemm_qkv<0><<<dim3(64,8,3), gb, 0, stream>>>(xq, xk, xv,
        WqT, WkT, WvT, bq, bk, bv, Qb, Kbf, Vt, f32f);
  }

  attn5<<<dim3(1024,1,1), gb, 0, stream>>>(Qb, Kbf, Vt, Qb /* O reuses Q */);

  gemm_o<<<dim3(64,8,1), gb, 0, stream>>>(Qb, WoT, bo, d_out, f32f);
}

// Round 12
// 343.279 us; speedup vs baseline: 1.1473x; 1.0129x over previous
//
#include <hip/hip_runtime.h>

typedef unsigned short u16;
typedef unsigned int   u32;
typedef unsigned long long u64;
typedef __attribute__((ext_vector_type(8))) short bf16x8;
typedef __attribute__((ext_vector_type(4))) float f32x4;

#define S_  2048
#define DH  64
#define DM  1024
#define BS  8192
#define CS  0.18033688011112042f   // 0.125 * log2(e)

static __device__ __forceinline__ float bf2f(u16 v){ return __uint_as_float(((u32)v)<<16); }
static __device__ __forceinline__ u16 f2bf(float f){
  u32 x = __float_as_uint(f);
  return (u16)((x + 0x7fffu + ((x>>16)&1u)) >> 16);   // RNE
}
#if __has_builtin(__builtin_amdgcn_cvt_pk_bf16_f32)
static __device__ __forceinline__ u32 pk2(float x, float y){
  typedef __attribute__((ext_vector_type(2))) __bf16 bf2v;
  union { bf2v v; u32 u; } c; c.v = __builtin_amdgcn_cvt_pk_bf16_f32(x, y); return c.u;
}
#else
static __device__ __forceinline__ u32 pk2(float x, float y){
  return (u32)f2bf(x) | ((u32)f2bf(y) << 16);
}
#endif
#if __has_builtin(__builtin_amdgcn_exp2f)
#define EXP2F(x) __builtin_amdgcn_exp2f(x)
#else
#define EXP2F(x) exp2f(x)
#endif

// async global->LDS, 16B/lane; LDS dest = wave-uniform base + lane*16
static __device__ __forceinline__ void dma16(const u16* g, const u16* l){
  __builtin_amdgcn_global_load_lds(
      (const __attribute__((address_space(1))) u32*)(u64)(uintptr_t)g,
      (__attribute__((address_space(3))) u32*)(u32)(u64)(uintptr_t)l, 16, 0, 0);
}

// 16B-aligned fragment load (single ds_read_b128)
static __device__ __forceinline__ bf16x8 frag16v(const u16* p){
  union { bf16x8 f; uint4 u; } w;
  w.u = *(const uint4*)p;
  return w.f;
}

// prep: z=0..3 -> weight transpose (f32/bf16 -> bf16, [k][n] -> [n][k]);
//       z=4..6 -> activation f32->bf16 convert (skipped when input is bf16).
// NOTE (session lesson, R3/R6/R8/R10): keeping the activation convert as a
// separate bandwidth-bound pass feeding global_load_lds-staged GEMMs beat
// every in-GEMM conversion variant by 70-90 us. Do not re-fuse.
__global__ __launch_bounds__(256) void prep(
    const void* __restrict__ w0, const void* __restrict__ w1,
    const void* __restrict__ w2, const void* __restrict__ w3,
    u16* t0, u16* t1, u16* t2, u16* t3,
    const void* __restrict__ a0, const void* __restrict__ a1,
    const void* __restrict__ a2,
    u16* c0, u16* c1, u16* c2, const int f32f){
  __shared__ u16 tile[32][33];
  int z = blockIdx.z;
  int tid = threadIdx.x;
  bool f32 = f32f != 0;
  if (z < 4){
    const void* in = z==0?w0 : z==1?w1 : z==2?w2 : w3;
    u16* out = z==0?t0 : z==1?t1 : z==2?t2 : t3;
    int tx = tid & 31, ty = tid >> 5;
    int c  = blockIdx.x*32 + tx;
    int r0 = blockIdx.y*32;
    for (int i=ty;i<32;i+=8){
      long off = (long)(r0+i)*DM + c;
      tile[i][tx] = f32 ? f2bf(((const float*)in)[off]) : ((const u16*)in)[off];
    }
    __syncthreads();
    int rr = r0 + tx, cb = blockIdx.x*32;
    for (int i=ty;i<32;i+=8) out[(long)(cb+i)*DM + rr] = tile[tx][i];
  } else {
    if (!f32) return;
    const void* in = z==4?a0 : z==5?a1 : a2;
    u16* out = z==4?c0 : z==5?c1 : c2;
    long lb = (long)blockIdx.y*32 + blockIdx.x;     // 0..1023
    long base = (lb*256 + tid)*8;
    #pragma unroll
    for (int it=0; it<4; it++){
      long i = base + (long)it*2097152;
      const float4* p = (const float4*)((const float*)in + i);
      float4 x = p[0], y = p[1];
      *(uint4*)(out + i) = make_uint4(pk2(x.x,x.y), pk2(x.z,x.w), pk2(y.x,y.y), pk2(y.z,y.w));
    }
  }
}

// ---------------- 256x128-tile GEMM core (8 waves, BK=64) ----------------
// Double-buffered LDS (96KB -> 1 block/CU), counted vmcnt(6) (never drains
// in the main loop), 32 MFMA per barrier pair (2x the 128^2 structure), and
// the R7-proven XOR swizzle generalized to 128B rows / 8 16B-slots:
//   phys_slot = slot ^ (row & 7)
// Staging: dma16 linear dest; source lane l covers row base+(l>>3), logical
// slot sl = (l&7)^(l>>3). Read: slot (kk*4+q) ^ (t&7) -> 16 lanes spread
// over all 8 slots x2 = conflict-free (2-way is free, m136).
// Grids are tail-free: qkv (32,8,3) = 768 blocks = exactly 3 rounds at
// 1 block/CU; gemm_o (32,8,1) = exactly 1 round.

// Fused QKV projection: z=0 -> Q (scaled by CS), z=1 -> K, z=2 -> V (written
// transposed per head with in-tile key permutation sigma:
//   n = rt*16 + q*4 + r  ->  p = 32*(rt>>1) + 8*q + 4*(rt&1) + r
// (unchanged under the 256-row tile: (s>>4)&3 == rt since wr*4 = 0 mod 4).
__global__ __launch_bounds__(512) void gemm_qkv(
    const u16* __restrict__ A0, const u16* __restrict__ A1, const u16* __restrict__ A2,
    const u16* __restrict__ W0, const u16* __restrict__ W1, const u16* __restrict__ W2,
    const void* __restrict__ bv0, const void* __restrict__ bv1, const void* __restrict__ bv2,
    u16* C0, u16* C1, u16* C2, const int f32f){
  __shared__ __align__(16) u16 As[2][256*64];   // 64KB
  __shared__ __align__(16) u16 Bs[2][128*64];   // 32KB
  int z = blockIdx.z;
  const u16* A  = z==0?A0 : z==1?A1 : A2;
  const u16* BT = z==0?W0 : z==1?W1 : W2;
  const void* bias = z==0?bv0 : z==1?bv1 : bv2;
  u16* C = z==0?C0 : z==1?C1 : C2;
  const bool bF32 = (f32f != 0);
  int tid = threadIdx.x;
  int by = blockIdx.x, bx = blockIdx.y;
  int lane = tid & 63, w = tid >> 6;          // w 0..7
  int t = lane & 15, q = lane >> 4;
  int wr = w >> 1, wc = w & 1;                // wave tile: rows wr*64, cols wc*64
  f32x4 acc[4][4];
  #pragma unroll
  for(int i=0;i<4;i++) for(int j=0;j<4;j++) for(int k=0;k<4;k++) acc[i][j][k]=0.f;

  // staging source mapping (per lane): row = base + (lane>>3), slot sl
  int sl = (lane & 7) ^ (lane >> 3);
  const u16* gA = A  + ((long)(by*256 + w*8 + (lane>>3))*DM + sl*8);
  const u16* gB = BT + ((long)(bx*128 + w*8 + (lane>>3))*DM + sl*8);

  // prologue: kt0 -> buf0, kt1 -> buf1 (6 loads each)
  #pragma unroll
  for (int i=0;i<4;i++) dma16(gA + (long)i*64*DM,      &As[0][(i*64 + w*8)*64]);
  #pragma unroll
  for (int j=0;j<2;j++) dma16(gB + (long)j*64*DM,      &Bs[0][(j*64 + w*8)*64]);
  #pragma unroll
  for (int i=0;i<4;i++) dma16(gA + (long)i*64*DM + 64, &As[1][(i*64 + w*8)*64]);
  #pragma unroll
  for (int j=0;j<2;j++) dma16(gB + (long)j*64*DM + 64, &Bs[1][(j*64 + w*8)*64]);

  for (int kt=0; kt<16; kt++){
    int buf = kt & 1;
    if (kt < 15) asm volatile("s_waitcnt vmcnt(6)" ::: "memory");  // kt landed; kt+1 in flight
    else         asm volatile("s_waitcnt vmcnt(0)" ::: "memory");
    __builtin_amdgcn_s_barrier();
    #pragma unroll
    for (int kk=0; kk<2; kk++){
      bf16x8 af[4], bfr[4];
      int so = (((kk*4 + q) ^ (t&7)) << 3);
      #pragma unroll
      for (int rt=0;rt<4;rt++) af[rt]  = frag16v(&As[buf][(wr*64 + rt*16 + t)*64 + so]);
      #pragma unroll
      for (int ct=0;ct<4;ct++) bfr[ct] = frag16v(&Bs[buf][(wc*64 + ct*16 + t)*64 + so]);
      __builtin_amdgcn_s_setprio(1);
      #pragma unroll
      for (int rt=0;rt<4;rt++)
        #pragma unroll
        for (int ct=0;ct<4;ct++)
          acc[rt][ct] = __builtin_amdgcn_mfma_f32_16x16x32_bf16(af[rt], bfr[ct], acc[rt][ct], 0,0,0);
      __builtin_amdgcn_s_setprio(0);
    }
    __builtin_amdgcn_s_barrier();
    if (kt + 2 < 16){
      int k0 = (kt+2)*64;
      #pragma unroll
      for (int i=0;i<4;i++) dma16(gA + (long)i*64*DM + k0, &As[buf][(i*64 + w*8)*64]);
      #pragma unroll
      for (int j=0;j<2;j++) dma16(gB + (long)j*64*DM + k0, &Bs[buf][(j*64 + w*8)*64]);
    }
  }

  float scale = (z==0) ? CS : 1.0f;
  #pragma unroll
  for (int ct=0;ct<4;ct++){
    int col = bx*128 + wc*64 + ct*16 + t;
    float bvv = bF32 ? ((const float*)bias)[col] : bf2f(((const u16*)bias)[col]);
    #pragma unroll
    for (int rt=0;rt<4;rt++){
      int row0 = by*256 + wr*64 + rt*16 + q*4;
      if (z == 2){
        int bb = row0 >> 11, s = row0 & 2047;
        long vbase = (long)bb*2097152 + (long)col*2048
                   + (s & ~63) + ((rt>>1)<<5) + (q<<3) + ((rt&1)<<2);
        u32 lo = pk2(acc[rt][ct][0]+bvv, acc[rt][ct][1]+bvv);
        u32 hi = pk2(acc[rt][ct][2]+bvv, acc[rt][ct][3]+bvv);
        *(uint2*)(C + vbase) = make_uint2(lo,hi);
      } else {
        #pragma unroll
        for (int r=0;r<4;r++)
          C[(long)(row0+r)*DM + col] = f2bf((acc[rt][ct][r] + bvv)*scale);
      }
    }
  }
}

// Output projection: same 256x128 core; C dtype per flag.
__global__ __launch_bounds__(512) void gemm_o(const u16* __restrict__ A,
    const u16* __restrict__ BT, const void* __restrict__ bias, void* __restrict__ C,
    const int f32f){
  __shared__ __align__(16) u16 As[2][256*64];
  __shared__ __align__(16) u16 Bs[2][128*64];
  const int f = f32f;
  int tid = threadIdx.x;
  int by = blockIdx.x, bx = blockIdx.y;
  int lane = tid & 63, w = tid >> 6;
  int t = lane & 15, q = lane >> 4;
  int wr = w >> 1, wc = w & 1;
  f32x4 acc[4][4];
  #pragma unroll
  for(int i=0;i<4;i++) for(int j=0;j<4;j++) for(int k=0;k<4;k++) acc[i][j][k]=0.f;

  int sl = (lane & 7) ^ (lane >> 3);
  const u16* gA = A  + ((long)(by*256 + w*8 + (lane>>3))*DM + sl*8);
  const u16* gB = BT + ((long)(bx*128 + w*8 + (lane>>3))*DM + sl*8);

  #pragma unroll
  for (int i=0;i<4;i++) dma16(gA + (long)i*64*DM,      &As[0][(i*64 + w*8)*64]);
  #pragma unroll
  for (int j=0;j<2;j++) dma16(gB + (long)j*64*DM,      &Bs[0][(j*64 + w*8)*64]);
  #pragma unroll
  for (int i=0;i<4;i++) dma16(gA + (long)i*64*DM + 64, &As[1][(i*64 + w*8)*64]);
  #pragma unroll
  for (int j=0;j<2;j++) dma16(gB + (long)j*64*DM + 64, &Bs[1][(j*64 + w*8)*64]);

  for (int kt=0; kt<16; kt++){
    int buf = kt & 1;
    if (kt < 15) asm volatile("s_waitcnt vmcnt(6)" ::: "memory");
    else         asm volatile("s_waitcnt vmcnt(0)" ::: "memory");
    __builtin_amdgcn_s_barrier();
    #pragma unroll
    for (int kk=0; kk<2; kk++){
      bf16x8 af[4], bfr[4];
      int so = (((kk*4 + q) ^ (t&7)) << 3);
      #pragma unroll
      for (int rt=0;rt<4;rt++) af[rt]  = frag16v(&As[buf][(wr*64 + rt*16 + t)*64 + so]);
      #pragma unroll
      for (int ct=0;ct<4;ct++) bfr[ct] = frag16v(&Bs[buf][(wc*64 + ct*16 + t)*64 + so]);
      __builtin_amdgcn_s_setprio(1);
      #pragma unroll
      for (int rt=0;rt<4;rt++)
        #pragma unroll
        for (int ct=0;ct<4;ct++)
          acc[rt][ct] = __builtin_amdgcn_mfma_f32_16x16x32_bf16(af[rt], bfr[ct], acc[rt][ct], 0,0,0);
      __builtin_amdgcn_s_setprio(0);
    }
    __builtin_amdgcn_s_barrier();
    if (kt + 2 < 16){
      int k0 = (kt+2)*64;
      #pragma unroll
      for (int i=0;i<4;i++) dma16(gA + (long)i*64*DM + k0, &As[buf][(i*64 + w*8)*64]);
      #pragma unroll
      for (int j=0;j<2;j++) dma16(gB + (long)j*64*DM + k0, &Bs[buf][(j*64 + w*8)*64]);
    }
  }

  #pragma unroll
  for (int ct=0;ct<4;ct++){
    int col = bx*128 + wc*64 + ct*16 + t;
    float bvv = f ? ((const float*)bias)[col] : bf2f(((const u16*)bias)[col]);
    #pragma unroll
    for (int rt=0;rt<4;rt++){
      int row0 = by*256 + wr*64 + rt*16 + q*4;
      #pragma unroll
      for (int r=0;r<4;r++){
        long idx = (long)(row0+r)*DM + col;
        float v = acc[rt][ct][r] + bvv;
        if (f) ((float*)C)[idx] = v;
        else   ((u16*)C)[idx]  = f2bf(v);
      }
    }
  }
}

// Flash attention v5b (R2/R7 schedule + zero-C first MFMA) — FROZEN.
// Swapped QK^T: mfma(K, Q) puts P[qrow=t][key=16c+4q+r] lane-local; V is
// stored (by gemm_qkv) with the sigma key-permutation so PV A-fragments are
// built entirely in-register (cvt_pk only): NO P LDS round-trip. Row sums
// via a constant ones-column B-fragment MFMA (o4). K/V double-buffered in
// stride-64 LDS via global_load_lds with XOR-pre-swizzled source. Two
// barriers/iter; prefetch issued before vmcnt(4) (race-free). LDS=32KB ->
// 4 blocks/CU (grid 1024, no tail).
__global__ __launch_bounds__(256,4) void attn5(const u16* __restrict__ Q,
    const u16* __restrict__ Kb, const u16* __restrict__ Vt, u16* __restrict__ O){
  __shared__ __align__(16) u16 Ks[2][4096];   // [buf][64 s-rows][64 d], swizzled
  __shared__ __align__(16) u16 Vs[2][4096];   // [buf][64 dh-rows][64 kpos], swizzled
  int tid = threadIdx.x;
  int bid = blockIdx.x;
  int qt = bid >> 6;
  int s6 = bid & 63;
  int bh = (s6 & 7)*8 + (s6 >> 3);   // all 16 qt-blocks of a bh share bid%8 -> same XCD
  int b = bh >> 4, h = bh & 15;
  int lane = tid & 63, w = tid >> 6;
  int t = lane & 15, q = lane >> 4;

  const u16* Qbase = Q + ((long)(b*S_ + qt*128 + w*32 + t)*DM + h*DH + q*8);
  bf16x8 qf[2][2];
  qf[0][0] = frag16v(Qbase);
  qf[0][1] = frag16v(Qbase + 32);
  qf[1][0] = frag16v(Qbase + 16*DM);
  qf[1][1] = frag16v(Qbase + 16*DM + 32);

  int r0 = tid >> 3;
  int cb = ((tid & 7) * 16) ^ ((r0 & 7) << 4);
  const char* gK = (const char*)Kb + (((long)(b*S_ + r0)*DM + h*DH) << 1) + cb;
  const char* gV = (const char*)Vt + ((((long)bh << 17) + ((long)r0 << 11)) << 1) + cb;
  const long gK1 = ((long)32*DM) << 1;     // +32 s-rows
  const long gV1 = ((long)32*S_) << 1;     // +32 dh-rows
  const int ld0 = w*512, ld1 = 2048 + w*512;   // wave-uniform LDS bases (u16)

  f32x4 o[2][4];
  #pragma unroll
  for (int i=0;i<2;i++) for (int j=0;j<4;j++) for (int k=0;k<4;k++) o[i][j][k]=0.f;
  f32x4 o4[2];
  #pragma unroll
  for (int i=0;i<2;i++) for (int k=0;k<4;k++) o4[i][k]=0.f;

  const f32x4 z4 = {0.f, 0.f, 0.f, 0.f};   // loop-invariant zero C operand

  union { bf16x8 f; u32 u[4]; } vone;
  { u32 ovv = (t==0) ? 0x3F803F80u : 0u;
    vone.u[0]=ovv; vone.u[1]=ovv; vone.u[2]=ovv; vone.u[3]=ovv; }

  const int xorv = (t & 7) << 4;   // read-side byte XOR (row&7 == t&7 for all frags)

  dma16((const u16*)(gK),       &Ks[0][ld0]);
  dma16((const u16*)(gK + gK1), &Ks[0][ld1]);
  dma16((const u16*)(gV),       &Vs[0][ld0]);
  dma16((const u16*)(gV + gV1), &Vs[0][ld1]);

  for (int kt=0; kt<32; kt++){
    int cur = kt & 1;
    if (kt < 31){
      long ko = ((long)(kt+1)*64*DM) << 1;   // K advances 64 s-rows
      long vo = (long)(kt+1) << 7;           // V advances 64 key-positions (128 B)
      dma16((const u16*)(gK + ko),       &Ks[cur^1][ld0]);
      dma16((const u16*)(gK + ko + gK1), &Ks[cur^1][ld1]);
      dma16((const u16*)(gV + vo),       &Vs[cur^1][ld0]);
      dma16((const u16*)(gV + vo + gV1), &Vs[cur^1][ld1]);
      asm volatile("s_waitcnt vmcnt(4)" ::: "memory");   // tile kt ready, kt+1 in flight
    } else {
      asm volatile("s_waitcnt vmcnt(0)" ::: "memory");
    }
    __builtin_amdgcn_s_barrier();

    const u16* Kc = Ks[cur];
    const u16* Vc = Vs[cur];

    f32x4 sacc[2][4];
    {
      int off = ((q*16) ^ xorv) >> 1;
      bf16x8 k0 = frag16v(Kc + (t     )*64 + off);
      bf16x8 k1 = frag16v(Kc + (16 + t)*64 + off);
      bf16x8 k2 = frag16v(Kc + (32 + t)*64 + off);
      bf16x8 k3 = frag16v(Kc + (48 + t)*64 + off);
      __builtin_amdgcn_s_setprio(1);
      #pragma unroll
      for (int rt=0; rt<2; rt++){
        sacc[rt][0] = __builtin_amdgcn_mfma_f32_16x16x32_bf16(k0, qf[rt][0], z4, 0,0,0);
        sacc[rt][1] = __builtin_amdgcn_mfma_f32_16x16x32_bf16(k1, qf[rt][0], z4, 0,0,0);
        sacc[rt][2] = __builtin_amdgcn_mfma_f32_16x16x32_bf16(k2, qf[rt][0], z4, 0,0,0);
        sacc[rt][3] = __builtin_amdgcn_mfma_f32_16x16x32_bf16(k3, qf[rt][0], z4, 0,0,0);
      }
      __builtin_amdgcn_s_setprio(0);
    }
    {
      int off = ((64 + q*16) ^ xorv) >> 1;
      bf16x8 k0 = frag16v(Kc + (t     )*64 + off);
      bf16x8 k1 = frag16v(Kc + (16 + t)*64 + off);
      bf16x8 k2 = frag16v(Kc + (32 + t)*64 + off);
      bf16x8 k3 = frag16v(Kc + (48 + t)*64 + off);
      __builtin_amdgcn_s_setprio(1);
      #pragma unroll
      for (int rt=0; rt<2; rt++){
        sacc[rt][0] = __builtin_amdgcn_mfma_f32_16x16x32_bf16(k0, qf[rt][1], sacc[rt][0],0,0,0);
        sacc[rt][1] = __builtin_amdgcn_mfma_f32_16x16x32_bf16(k1, qf[rt][1], sacc[rt][1],0,0,0);
        sacc[rt][2] = __builtin_amdgcn_mfma_f32_16x16x32_bf16(k2, qf[rt][1], sacc[rt][2],0,0,0);
        sacc[rt][3] = __builtin_amdgcn_mfma_f32_16x16x32_bf16(k3, qf[rt][1], sacc[rt][3],0,0,0);
      }
      __builtin_amdgcn_s_setprio(0);
    }

    union { bf16x8 f; u32 u[4]; } af[2][2];
    #pragma unroll
    for (int rt=0; rt<2; rt++){
      float ev[4][4];
      #pragma unroll
      for (int c=0; c<4; c++)
        #pragma unroll
        for (int r=0; r<4; r++) ev[c][r] = EXP2F(sacc[rt][c][r]);
      #pragma unroll
      for (int ks=0; ks<2; ks++){
        af[rt][ks].u[0] = pk2(ev[2*ks  ][0], ev[2*ks  ][1]);
        af[rt][ks].u[1] = pk2(ev[2*ks  ][2], ev[2*ks  ][3]);
        af[rt][ks].u[2] = pk2(ev[2*ks+1][0], ev[2*ks+1][1]);
        af[rt][ks].u[3] = pk2(ev[2*ks+1][2], ev[2*ks+1][3]);
      }
    }

    #pragma unroll
    for (int ks=0; ks<2; ks++){
      int off = ((ks*64 + q*16) ^ xorv) >> 1;
      bf16x8 v0 = frag16v(Vc + (t     )*64 + off);
      bf16x8 v1 = frag16v(Vc + (16 + t)*64 + off);
      bf16x8 v2 = frag16v(Vc + (32 + t)*64 + off);
      bf16x8 v3 = frag16v(Vc + (48 + t)*64 + off);
      __builtin_amdgcn_s_setprio(1);
      #pragma unroll
      for (int rt=0; rt<2; rt++){
        o[rt][0] = __builtin_amdgcn_mfma_f32_16x16x32_bf16(af[rt][ks].f, v0, o[rt][0],0,0,0);
        o[rt][1] = __builtin_amdgcn_mfma_f32_16x16x32_bf16(af[rt][ks].f, v1, o[rt][1],0,0,0);
        o[rt][2] = __builtin_amdgcn_mfma_f32_16x16x32_bf16(af[rt][ks].f, v2, o[rt][2],0,0,0);
        o[rt][3] = __builtin_amdgcn_mfma_f32_16x16x32_bf16(af[rt][ks].f, v3, o[rt][3],0,0,0);
        o4[rt]   = __builtin_amdgcn_mfma_f32_16x16x32_bf16(af[rt][ks].f, vone.f, o4[rt],0,0,0);
      }
      __builtin_amdgcn_s_setprio(0);
    }
    __builtin_amdgcn_s_barrier();
  }

  #pragma unroll
  for (int rt=0; rt<2; rt++){
    #pragma unroll
    for (int r=0; r<4; r++){
      float l = __shfl(o4[rt][r], lane & 48);
      float inv = 1.f / l;
      int row = qt*128 + w*32 + rt*16 + q*4 + r;
      #pragma unroll
      for (int ct=0; ct<4; ct++)
        O[(long)(b*S_ + row)*DM + h*DH + ct*16 + t] = f2bf(o[rt][ct][r] * inv);
    }
  }
}

extern "C" void kernel_launch(void* const* d_in, const int* in_sizes, int n_in,
                              void* d_out, int out_size, void* d_ws, size_t ws_size,
                              hipStream_t stream){
  (void)n_in; (void)out_size; (void)ws_size;
  const void* xq = d_in[0];
  const void* xk = d_in[1];
  const void* xv = d_in[2];
  const void* Wq = d_in[3];
  const void* bq = d_in[4];
  const void* Wk = d_in[5];
  const void* bk = d_in[6];
  const void* Wv = d_in[7];
  const void* bv = d_in[8];
  const void* Wo = d_in[9];
  const void* bo = d_in[10];

  // dtype from host-side size: bf16 iff input 0 is exactly NT*2 bytes.
  const long NT = (long)BS*DM;                    // 8,388,608 elements
  int f32f = 1;
  if (in_sizes && in_sizes[0] == (int)(NT*2)) f32f = 0;

  u16* base = (u16*)((char*)d_ws + 256);
  u16* Qb  = base;                                // Q (scaled), later attention O
  u16* Kbf = base + NT;
  u16* Vt  = base + 2*NT;                         // [b*16+h][64][2048], sigma-permuted
  u16* WqT = base + 3*NT;
  u16* WkT = WqT + (long)DM*DM;
  u16* WvT = WkT + (long)DM*DM;
  u16* WoT = WvT + (long)DM*DM;
  u16* Xc0 = WoT + (long)DM*DM;                   // bf16-converted activations
  u16* Xc1 = Xc0 + NT;
  u16* Xc2 = Xc1 + NT;

  dim3 gb(256,1,1);
  int nz = f32f ? 7 : 4;
  prep<<<dim3(32,32,nz), gb, 0, stream>>>(Wq, Wk, Wv, Wo,
      WqT, WkT, WvT, WoT, xq, xk, xv, Xc0, Xc1, Xc2, f32f);

  const u16* Aq = f32f ? Xc0 : (const u16*)xq;
  const u16* Ak = f32f ? Xc1 : (const u16*)xk;
  const u16* Av = f32f ? Xc2 : (const u16*)xv;
  gemm_qkv<<<dim3(32,8,3), dim3(512,1,1), 0, stream>>>(Aq, Ak, Av,
      WqT, WkT, WvT, bq, bk, bv, Qb, Kbf, Vt, f32f);

  attn5<<<dim3(1024,1,1), gb, 0, stream>>>(Qb, Kbf, Vt, Qb /* O reuses Q */);

  gemm_o<<<dim3(32,8,1), dim3(512,1,1), 0, stream>>>(Qb, WoT, bo, d_out, f32f);
}